// Round 8
// baseline (522.435 us; speedup 1.0000x reference)
//
#include <hip/hip_runtime.h>
#include <hip/hip_bf16.h>

// Decoder block: B=2, T=2048, E=1024, H=16, D=64
// Inputs/outputs FP32; internals bf16 MFMA + fp32 accumulate.
// R18: bigger per-wave GEMM tiles for FC+QKV. R17 re-anchored 422.8us with
// flash=R12(83.8) + R13 GEMM stack. FC GEMM accounting: ~5000cy/CU-round vs
// ~1150cy LDS + ~310cy MFMA demand => ~70% barrier-synced latency stall, only
// 16 MFMA/wave bought per barrier. Fix: TM=256,TN=128 (same kernel template,
// same wave map) -> per-wave 128x64 tile = 32 MFMA + 12 ds_read per barrier
// (2x MFMA/barrier, better MFMA:LDS ratio). LOADS=6, NBUF=3, LDS 72KB ->
// 2 blocks/CU; VGPR ~210 -> 2 waves/SIMD consistent. FC grid 512 = exactly
// 2/CU, no scheduling tail (was 1024@3-resident). QKV same. Wo/proj/flash
// byte-identical to R17. Spill tripwire: VGPR>=256 / WRITE_SIZE balloon.

#define TT 2048
#define EE 1024
#define NH 16
#define HD 64

#define AS1 __attribute__((address_space(1)))
#define AS3 __attribute__((address_space(3)))

using bf16x8 = __bf16 __attribute__((ext_vector_type(8)));
using bf16x4 = __bf16 __attribute__((ext_vector_type(4)));
using f32x4  = float __attribute__((ext_vector_type(4)));

// counted vmem wait; literal immediates only (asm cannot paste computed N)
template<int N> __device__ __forceinline__ void vm_wait() {
    if constexpr (N == 0)      asm volatile("s_waitcnt vmcnt(0)" ::: "memory");
    else if constexpr (N == 2) asm volatile("s_waitcnt vmcnt(2)" ::: "memory");
    else if constexpr (N == 3) asm volatile("s_waitcnt vmcnt(3)" ::: "memory");
    else if constexpr (N == 4) asm volatile("s_waitcnt vmcnt(4)" ::: "memory");
    else if constexpr (N == 6) asm volatile("s_waitcnt vmcnt(6)" ::: "memory");
    else                       asm volatile("s_waitcnt vmcnt(8)" ::: "memory");
}

// fast erf-based exact GELU: A&S 7.1.26, |err| <= 1.5e-7 (vs erff ~50 VALU)
__device__ __forceinline__ float gelu_fast(float v) {
    float z  = v * 0.70710678118f;
    float az = fabsf(z);
    float t  = __builtin_amdgcn_rcpf(__builtin_fmaf(0.3275911f, az, 1.0f));
    float p  = t * __builtin_fmaf(t,
                   __builtin_fmaf(t,
                     __builtin_fmaf(t,
                       __builtin_fmaf(t, 1.061405429f, -1.453152027f),
                       1.421413741f),
                     -0.284496736f),
                   0.254829592f);
    float e  = __expf(-az * az);
    float er = copysignf(1.0f - p * e, z);
    return 0.5f * v * (1.0f + er);
}

// ---------------- fp32 [K][N] -> bf16 [N][K] tiled transpose-convert ------------
__global__ __launch_bounds__(256) void convt_kernel(const float* __restrict__ W,
                                                    __bf16* __restrict__ WT,
                                                    int K, int N) {
    __shared__ __bf16 t[32][33];
    int n0 = blockIdx.x * 32, k0 = blockIdx.y * 32;
    int tid = threadIdx.x;
    int r = tid >> 3, c4 = (tid & 7) * 4;
    float4 v = *(const float4*)(W + (size_t)(k0 + r) * N + n0 + c4);
    t[r][c4 + 0] = (__bf16)v.x; t[r][c4 + 1] = (__bf16)v.y;
    t[r][c4 + 2] = (__bf16)v.z; t[r][c4 + 3] = (__bf16)v.w;
    __syncthreads();
    bf16x4 o;
    o[0] = t[c4 + 0][r]; o[1] = t[c4 + 1][r];
    o[2] = t[c4 + 2][r]; o[3] = t[c4 + 3][r];
    *(bf16x4*)(WT + (size_t)(n0 + r) * K + k0 + c4) = o;
}

// ---------------- LayerNorm: fp32 in -> bf16 out. One block per row of 1024. ----
__global__ __launch_bounds__(256) void ln_kernel(const float* __restrict__ x,
                                                 const float* __restrict__ g,
                                                 const float* __restrict__ bta,
                                                 __bf16* __restrict__ out) {
    int row = blockIdx.x;
    int tid = threadIdx.x;
    const float4 xv = *(const float4*)(x + (size_t)row * EE + tid * 4);
    float s  = xv.x + xv.y + xv.z + xv.w;
    float ss = xv.x*xv.x + xv.y*xv.y + xv.z*xv.z + xv.w*xv.w;
    __shared__ float rs[256], rss[256];
    rs[tid] = s; rss[tid] = ss;
    __syncthreads();
    for (int st = 128; st > 0; st >>= 1) {
        if (tid < st) { rs[tid] += rs[tid+st]; rss[tid] += rss[tid+st]; }
        __syncthreads();
    }
    float mean = rs[0] * (1.0f / EE);
    float var  = rss[0] * (1.0f / EE) - mean * mean;
    float rstd = rsqrtf(var + 1e-5f);
    const float4 gv = *(const float4*)(g + tid * 4);
    const float4 bv = *(const float4*)(bta + tid * 4);
    bf16x4 ov;
    ov[0] = (__bf16)((xv.x - mean) * rstd * gv.x + bv.x);
    ov[1] = (__bf16)((xv.y - mean) * rstd * gv.y + bv.y);
    ov[2] = (__bf16)((xv.z - mean) * rstd * gv.z + bv.z);
    ov[3] = (__bf16)((xv.w - mean) * rstd * gv.w + bv.w);
    *(bf16x4*)(out + (size_t)row * EE + tid * 4) = ov;
}

// ---------------- pipelined GEMM (QKV mode adds V-transpose epilogue) ------------
// NBUF LDS buffers, prefetch DEPTH=NBUF-1 K-steps ahead, counted vmcnt, raw
// s_barrier. LDS layout is slot-swizzled: logical 16B slot s of row r lives at
// phys slot s^((r>>1)&3). global_load_lds writes linearly, so STAGE pre-swizzles
// the GLOBAL source column; ds_read applies the same XOR (conflicts = 0, R12).
// Wave map: 4 waves as 2x2; per-wave tile = (TM/2)x(TN/2) = MT x NT fragments.
// TM=256,TN=128 -> 32 MFMA + 12 ds_read/wave/barrier (R18). ATOMIC: split-K x2
// over blockIdx.z, fp32 atomicAdd epilogue (bias at z==0).
template<int TM, int TN, bool GELU, bool RESID, bool QKV, bool ATOMIC, typename CT>
__global__ __launch_bounds__(256) void gemm_bt_kernel(const __bf16* __restrict__ A,
                                                      const __bf16* __restrict__ BT,
                                                      const float* __restrict__ bias,
                                                      const float* resid, CT* C,
                                                      __bf16* vT,
                                                      int M, int N, int K) {
    constexpr int MT = TM / 32;
    constexpr int NT = TN / 32;
    constexpr int LOADS = TM / 64 + TN / 64;   // global_load_lds per thread per stage
    constexpr int NBUF  = ATOMIC ? 3 : ((LOADS <= 3) ? 4 : 3);
    constexpr int DEPTH = NBUF - 1;
    constexpr int WAITN = (DEPTH - 1) * LOADS;
    __shared__ __align__(16) __bf16 As[NBUF][TM][32];
    __shared__ __align__(16) __bf16 Bs[NBUF][TN][32];
    int tid = threadIdx.x, wave = tid >> 6, lane = tid & 63;
    int quad = lane >> 4, l16 = lane & 15;
    int wm = wave >> 1, wn = wave & 1;
    int m0 = blockIdx.y * TM, n0 = blockIdx.x * TN;

    const int klen = ATOMIC ? (K >> 1) : K;
    const int koff = ATOMIC ? (int)blockIdx.z * klen : 0;

    f32x4 acc[MT][NT] = {};

    int srow = wave * 16 + (lane >> 2);
    // pre-swizzled global source column: phys slot lane&3 at row ..(lane>>2)
    // must hold logical slot (lane&3)^((row>>1)&3) = (lane&3)^((lane>>3)&3)
    int scol = (((lane & 3) ^ ((lane >> 3) & 3)) * 8);
    // ds_read column for logical slot `quad` of row ..+l16
    int xcol = ((quad ^ ((l16 >> 1) & 3)) * 8);

    auto STAGE = [&](int buf, int kt) {
        int kb = koff + (kt << 5);
#pragma unroll
        for (int p = 0; p < TM / 64; p++) {
            const __bf16* g = A + (size_t)(m0 + p * 64 + srow) * K + kb + scol;
            __builtin_amdgcn_global_load_lds((AS1 const void*)g,
                                             (AS3 void*)&As[buf][p * 64 + wave * 16][0],
                                             16, 0, 0);
        }
#pragma unroll
        for (int p = 0; p < TN / 64; p++) {
            const __bf16* g = BT + (size_t)(n0 + p * 64 + srow) * K + kb + scol;
            __builtin_amdgcn_global_load_lds((AS1 const void*)g,
                                             (AS3 void*)&Bs[buf][p * 64 + wave * 16][0],
                                             16, 0, 0);
        }
    };

    auto COMPUTE = [&](int cur) {
        bf16x8 af[MT], bfr[NT];
#pragma unroll
        for (int mt = 0; mt < MT; mt++)
            af[mt] = *(const bf16x8*)(&As[cur][wm * (MT * 16) + mt * 16 + l16][xcol]);
#pragma unroll
        for (int nt = 0; nt < NT; nt++)
            bfr[nt] = *(const bf16x8*)(&Bs[cur][wn * (NT * 16) + nt * 16 + l16][xcol]);
#pragma unroll
        for (int mt = 0; mt < MT; mt++)
#pragma unroll
            for (int nt = 0; nt < NT; nt++)
                acc[mt][nt] = __builtin_amdgcn_mfma_f32_16x16x32_bf16(af[mt], bfr[nt],
                                                                      acc[mt][nt], 0, 0, 0);
    };

    const int nk = klen >> 5;
#pragma unroll
    for (int i = 0; i < DEPTH; ++i) STAGE(i, i);
    vm_wait<WAITN>();               // stage(0) landed; rest stay in flight
    __builtin_amdgcn_s_barrier();

    int t = 0;
    for (; t + DEPTH < nk; ++t) {
        STAGE((t + DEPTH) % NBUF, t + DEPTH);
        COMPUTE(t % NBUF);
        vm_wait<WAITN>();           // stage(t+1) landed; newer stages in flight
        __builtin_amdgcn_s_barrier();
    }
    for (; t < nk; ++t) {           // tail: nothing left to issue
        COMPUTE(t % NBUF);
        if (t + 1 < nk) {
            int rem = nk - 2 - t;   // stages in flight beyond t+1
            if (rem >= 1) vm_wait<LOADS>();
            else          vm_wait<0>();
            __builtin_amdgcn_s_barrier();
        }
    }

#pragma unroll
    for (int nt = 0; nt < NT; nt++) {
        int c = n0 + wn * (NT * 16) + nt * 16 + l16;
        float bv = (!ATOMIC || blockIdx.z == 0) ? bias[c] : 0.0f;
#pragma unroll
        for (int mt = 0; mt < MT; mt++) {
#pragma unroll
            for (int r = 0; r < 4; r++) {
                int row = m0 + wm * (MT * 16) + mt * 16 + quad * 4 + r;
                float v = acc[mt][nt][r] + bv;
                if (GELU)  v = gelu_fast(v);
                if (RESID) v += resid[(size_t)row * N + c];
                if (ATOMIC) {
                    atomicAdd((float*)&C[(size_t)row * N + c], v);
                } else if (!QKV) {
                    C[(size_t)row * N + c] = (CT)v;
                } else {
                    if (c < 2 * EE) {
                        ((__bf16*)C)[(size_t)row * (2 * EE) + c] = (__bf16)v;
                    } else {
                        int cv = c - 2 * EE;          // cv = h*64 + d
                        int bb = row >> 11, tt = row & (TT - 1);
                        vT[((size_t)(bb * NH + (cv >> 6)) * HD + (cv & 63)) * TT + tt] =
                            (__bf16)v;
                    }
                }
            }
        }
    }
}

// ---------------- MFMA flash attention (R12 exact: paired q-tiles, equal work) ---
// qkv: [b][t][2E] (Q at h*64, K at EE+h*64). vT: [b][h][d][T].
// Block x handles q-tiles (31-x) then (x): 17 iters for every block.
__global__ __launch_bounds__(256) void flash_attn_kernel(const __bf16* __restrict__ qkv,
                                                         const __bf16* __restrict__ vT,
                                                         __bf16* __restrict__ out) {
    int h = blockIdx.y, b = blockIdx.z;
    int tid = threadIdx.x, wave = tid >> 6, lane = tid & 63;
    int quad = lane >> 4, l16 = lane & 15;

    __shared__ __align__(16) __bf16 Ks[128 * 72];
    __shared__ __align__(16) __bf16 Ps[4][16 * 136];

    size_t base = (size_t)b * TT * (2 * EE);

    int srow = tid >> 3;            // 0..31
    int scol = (tid & 7) * 8;
    const __bf16* kbase  = qkv + base + EE + h * HD + scol;
    const __bf16* vrow = vT + (size_t)(b * NH + h) * HD * TT + (size_t)l16 * TT + quad * 8;
    __bf16* Psw = &Ps[wave][0];

    int nTiles = (int)gridDim.x * 2;  // 32

    for (int pass = 0; pass < 2; pass++) {
        int qt = pass == 0 ? (nTiles - 1 - blockIdx.x) : blockIdx.x;
        int q0 = qt * 64;

        // Q A-fragments: A[m=l16][k=quad*8+j]
        int qrow = q0 + wave * 16 + l16;
        const __bf16* qp = qkv + base + (size_t)qrow * (2 * EE) + h * HD;
        bf16x8 aq0 = *(const bf16x8*)(qp + quad * 8);
        bf16x8 aq1 = *(const bf16x8*)(qp + 32 + quad * 8);

        f32x4 oacc[4] = {};
        float lsum[4] = {0.f, 0.f, 0.f, 0.f};
        int qg_base = q0 + wave * 16 + quad * 4;

        int nIter = (qt >> 1) + 1;

        bf16x8 kr[4];
#pragma unroll
        for (int p = 0; p < 4; p++)
            kr[p] = *(const bf16x8*)(kbase + (size_t)(32 * p + srow) * (2 * EE));

        for (int kt = 0; kt < nIter; ++kt) {
            int k0 = kt * 128;
            // ---- stage K ----
#pragma unroll
            for (int p = 0; p < 4; p++)
                *(bf16x8*)(&Ks[(32 * p + srow) * 72 + scol]) = kr[p];
            __syncthreads();  // B1

            // ---- issue this tile's V fragments (latency hides under QK+exp) ----
            bf16x8 vf[4][4];
#pragma unroll
            for (int dt = 0; dt < 4; dt++)
#pragma unroll
                for (int w = 0; w < 4; w++)
                    vf[dt][w] = *(const bf16x8*)(vrow + (size_t)dt * (16 * TT) + k0 + w * 32);

            // ---- prefetch next K tile ----
            if (kt < nIter - 1) {
                int kn = k0 + 128;
#pragma unroll
                for (int p = 0; p < 4; p++)
                    kr[p] = *(const bf16x8*)(kbase + (size_t)(kn + 32 * p + srow) * (2 * EE));
            }

            // ---- S = Q K^T over 128 keys ----
            f32x4 s[8];
#pragma unroll
            for (int nt = 0; nt < 8; nt++) {
                bf16x8 bk0 = *(const bf16x8*)(&Ks[(nt * 16 + l16) * 72 + quad * 8]);
                bf16x8 bk1 = *(const bf16x8*)(&Ks[(nt * 16 + l16) * 72 + 32 + quad * 8]);
                f32x4 z = {};
                z = __builtin_amdgcn_mfma_f32_16x16x32_bf16(aq0, bk0, z, 0, 0, 0);
                s[nt] = __builtin_amdgcn_mfma_f32_16x16x32_bf16(aq1, bk1, z, 0, 0, 0);
            }

            // ---- p = exp(s/8) (m=0; bounded, clamp), private swizzled Ps ----
            bool maskt = (kt == nIter - 1);
#pragma unroll
            for (int nt = 0; nt < 8; nt++) {
                int key = k0 + nt * 16 + l16;
                int cb = 2 * nt + (l16 >> 3);
#pragma unroll
                for (int r = 0; r < 4; r++) {
                    float p;
                    if (maskt && key > qg_base + r) p = 0.0f;
                    else p = __expf(fminf(s[nt][r] * 0.125f, 30.0f));
                    lsum[r] += p;
                    int q = quad * 4 + r;
                    int col = (((cb & 8) | ((cb - 2 * q) & 7)) << 3) | (l16 & 7);
                    Psw[q * 136 + col] = (__bf16)p;
                }
            }

            // ---- O += P V : Ps private (no barrier), V already in registers ----
#pragma unroll
            for (int w = 0; w < 4; w++) {
                int cbr = 4 * w + quad;
                int colr = ((cbr & 8) | ((cbr - 2 * l16) & 7)) << 3;
                bf16x8 ap = *(const bf16x8*)(&Psw[l16 * 136 + colr]);
#pragma unroll
                for (int dt = 0; dt < 4; dt++)
                    oacc[dt] = __builtin_amdgcn_mfma_f32_16x16x32_bf16(ap, vf[dt][w],
                                                                       oacc[dt], 0, 0, 0);
            }
            __syncthreads();  // B2: Ks reads done before next stage
        }

        // ---- deferred l reduce + epilogue for this q-tile ----
#pragma unroll
        for (int off = 1; off < 16; off <<= 1)
#pragma unroll
            for (int r = 0; r < 4; r++) lsum[r] += __shfl_xor(lsum[r], off);
#pragma unroll
        for (int dt = 0; dt < 4; dt++) {
#pragma unroll
            for (int r = 0; r < 4; r++) {
                int qg = qg_base + r;
                out[((size_t)b * TT + qg) * EE + h * HD + dt * 16 + l16] =
                    (__bf16)(oacc[dt][r] / lsum[r]);
            }
        }
    }
}

extern "C" void kernel_launch(void* const* d_in, const int* in_sizes, int n_in,
                              void* d_out, int out_size, void* d_ws, size_t ws_size,
                              hipStream_t stream) {
    const float* x     = (const float*)d_in[0];
    const float* ln1g  = (const float*)d_in[1];
    const float* ln1b  = (const float*)d_in[2];
    const float* ln2g  = (const float*)d_in[3];
    const float* ln2b  = (const float*)d_in[4];
    const float* Wqkv  = (const float*)d_in[5];
    const float* bqkv  = (const float*)d_in[6];
    const float* Wo    = (const float*)d_in[7];
    const float* bo    = (const float*)d_in[8];
    const float* Wfc   = (const float*)d_in[9];
    const float* bfc   = (const float*)d_in[10];
    const float* Wproj = (const float*)d_in[11];
    const float* bproj = (const float*)d_in[12];
    float* out = (float*)d_out;

    const int M = 2 * TT;  // 4096 tokens

    // Workspace (bf16, 50.4 MB), lifetime-aliased:
    //   regQ [0,16.8M): qkv(QK, 8.4M) | vT(4.2M) | WqkvT(3.15M) | WoT(1.05M)
    //                   -> all dead before ff [16.8M] overwrites
    //   regS [16.8M,21M): h1 -> atn -> h2 -> WprojT
    //   WfcT [21M,25.2M);  x1 (fp32) lives in d_out
    __bf16* ws = (__bf16*)d_ws;
    __bf16* regQ   = ws;
    __bf16* regS   = ws + 16777216;
    __bf16* WfcT   = ws + 20971520;
    __bf16* qkv    = regQ;                  //  8,388,608
    __bf16* vT     = regQ + 8388608;        //  4,194,304
    __bf16* WqkvT  = regQ + 12582912;       //  3,145,728
    __bf16* WoT    = regQ + 15728640;       //  1,048,576
    __bf16* ff     = regQ;
    __bf16* h1 = regS, *atn = regS, *h2 = regS;
    __bf16* WprojT = regS;
    float*  x1 = out;

    convt_kernel<<<dim3(3 * EE / 32, EE / 32), 256, 0, stream>>>(Wqkv, WqkvT, EE, 3 * EE);
    convt_kernel<<<dim3(EE / 32, EE / 32), 256, 0, stream>>>(Wo, WoT, EE, EE);
    convt_kernel<<<dim3(4 * EE / 32, EE / 32), 256, 0, stream>>>(Wfc, WfcT, EE, 4 * EE);

    ln_kernel<<<M, 256, 0, stream>>>(x, ln1g, ln1b, h1);
    // R18: 256x128 tile (32 MFMA/wave/barrier), grid 24x16 = 384 blocks
    gemm_bt_kernel<256, 128, false, false, true, false, __bf16>
        <<<dim3(3 * EE / 128, M / 256), 256, 0, stream>>>(
        h1, WqkvT, bqkv, nullptr, qkv, vT, M, 3 * EE, EE);
    flash_attn_kernel<<<dim3(TT / 128, NH, 2), 256, 0, stream>>>(qkv, vT, atn);
    gemm_bt_kernel<128, 64, false, true, false, false, float>
        <<<dim3(EE / 64, M / 128), 256, 0, stream>>>(
        atn, WoT, bo, x, x1, nullptr, M, EE, EE);
    ln_kernel<<<M, 256, 0, stream>>>(x1, ln2g, ln2b, h2);
    // R18: 256x128 tile, grid 32x16 = 512 blocks = exactly 2/CU, no tail
    gemm_bt_kernel<256, 128, true, false, false, false, __bf16>
        <<<dim3(4 * EE / 128, M / 256), 256, 0, stream>>>(
        h2, WfcT, bfc, nullptr, ff, nullptr, M, 4 * EE, EE);
    convt_kernel<<<dim3(EE / 32, 4 * EE / 32), 256, 0, stream>>>(Wproj, WprojT, 4 * EE, EE);
    // split-K x2: out already holds x1 (residual); halves atomicAdd partials.
    gemm_bt_kernel<128, 64, false, false, false, true, float>
        <<<dim3(EE / 64, M / 128, 2), 256, 0, stream>>>(
        ff, WprojT, bproj, nullptr, out, nullptr, M, EE, 4 * EE);
}

// Round 10
// 414.331 us; speedup vs baseline: 1.2609x; 1.2609x over previous
//
#include <hip/hip_runtime.h>
#include <hip/hip_bf16.h>

// Decoder block: B=2, T=2048, E=1024, H=16, D=64
// Inputs/outputs FP32; internals bf16 MFMA + fp32 accumulate.
// R20 = R19 resubmitted verbatim (R9 bench was an infra failure: "MI355X
// container failed twice"; kernel never ran). R19 content:
// GEMMs reverted to R17 exactly (R18's 256x128 tile: occupancy 8.2%, 109us,
// conclusively worse; 128x128@3/CU is this structure's optimum).
// Flash: (a) T1 bijective XCD clustering -- decode (h,b,qidx) from 1-D grid
// so each XCD owns 4 whole (h,b) pairs; KV (512KB/head) becomes L2-resident
// per-XCD instead of 8x-replicated (FETCH 97.8MB ~= 8x16MB KV confirms).
// Flash is latency-bound => HBM->L2 hit conversion shortens exposed windows.
// Paired q-tiles keep every block at exactly 17 iters so clustering costs no
// balance. (b) T5 setprio(1) around QK and PV MFMA clusters (m191 +4-7%).
// (c) 3 leading convt launches merged into one segmented kernel (13->11
// launches). Predicted: flash FETCH ~40MB, dur 72-77us; total ~405-412us.

#define TT 2048
#define EE 1024
#define NH 16
#define HD 64

#define AS1 __attribute__((address_space(1)))
#define AS3 __attribute__((address_space(3)))

using bf16x8 = __bf16 __attribute__((ext_vector_type(8)));
using bf16x4 = __bf16 __attribute__((ext_vector_type(4)));
using f32x4  = float __attribute__((ext_vector_type(4)));

// counted vmem wait; literal immediates only (asm cannot paste computed N)
template<int N> __device__ __forceinline__ void vm_wait() {
    if constexpr (N == 0)      asm volatile("s_waitcnt vmcnt(0)" ::: "memory");
    else if constexpr (N == 2) asm volatile("s_waitcnt vmcnt(2)" ::: "memory");
    else if constexpr (N == 3) asm volatile("s_waitcnt vmcnt(3)" ::: "memory");
    else if constexpr (N == 4) asm volatile("s_waitcnt vmcnt(4)" ::: "memory");
    else if constexpr (N == 6) asm volatile("s_waitcnt vmcnt(6)" ::: "memory");
    else                       asm volatile("s_waitcnt vmcnt(8)" ::: "memory");
}

// fast erf-based exact GELU: A&S 7.1.26, |err| <= 1.5e-7 (vs erff ~50 VALU)
__device__ __forceinline__ float gelu_fast(float v) {
    float z  = v * 0.70710678118f;
    float az = fabsf(z);
    float t  = __builtin_amdgcn_rcpf(__builtin_fmaf(0.3275911f, az, 1.0f));
    float p  = t * __builtin_fmaf(t,
                   __builtin_fmaf(t,
                     __builtin_fmaf(t,
                       __builtin_fmaf(t, 1.061405429f, -1.453152027f),
                       1.421413741f),
                     -0.284496736f),
                   0.254829592f);
    float e  = __expf(-az * az);
    float er = copysignf(1.0f - p * e, z);
    return 0.5f * v * (1.0f + er);
}

// ---------------- fp32 [K][N] -> bf16 [N][K] tiled transpose-convert ------------
__global__ __launch_bounds__(256) void convt_kernel(const float* __restrict__ W,
                                                    __bf16* __restrict__ WT,
                                                    int K, int N) {
    __shared__ __bf16 t[32][33];
    int n0 = blockIdx.x * 32, k0 = blockIdx.y * 32;
    int tid = threadIdx.x;
    int r = tid >> 3, c4 = (tid & 7) * 4;
    float4 v = *(const float4*)(W + (size_t)(k0 + r) * N + n0 + c4);
    t[r][c4 + 0] = (__bf16)v.x; t[r][c4 + 1] = (__bf16)v.y;
    t[r][c4 + 2] = (__bf16)v.z; t[r][c4 + 3] = (__bf16)v.w;
    __syncthreads();
    bf16x4 o;
    o[0] = t[c4 + 0][r]; o[1] = t[c4 + 1][r];
    o[2] = t[c4 + 2][r]; o[3] = t[c4 + 3][r];
    *(bf16x4*)(WT + (size_t)(n0 + r) * K + k0 + c4) = o;
}

// ---------------- merged transpose for the 3 leading weights (1 launch) ---------
// seg0: Wqkv K=EE N=3EE (96x32 tiles = 3072); seg1: Wo K=EE N=EE (1024);
// seg2: Wfc K=EE N=4EE (4096). total 8192 blocks.
__global__ __launch_bounds__(256) void convt3_kernel(const float* __restrict__ W0,
                                                     __bf16* __restrict__ T0,
                                                     const float* __restrict__ W1,
                                                     __bf16* __restrict__ T1,
                                                     const float* __restrict__ W2,
                                                     __bf16* __restrict__ T2) {
    __shared__ __bf16 t[32][33];
    int bt = blockIdx.x;
    const float* W; __bf16* WT; int N, nx;
    if (bt < 3072)      {            W = W0; WT = T0; N = 3 * EE; nx = 96;  }
    else if (bt < 4096) { bt -= 3072; W = W1; WT = T1; N = EE;     nx = 32;  }
    else                { bt -= 4096; W = W2; WT = T2; N = 4 * EE; nx = 128; }
    const int K = EE;
    int n0 = (bt % nx) * 32, k0 = (bt / nx) * 32;
    int tid = threadIdx.x;
    int r = tid >> 3, c4 = (tid & 7) * 4;
    float4 v = *(const float4*)(W + (size_t)(k0 + r) * N + n0 + c4);
    t[r][c4 + 0] = (__bf16)v.x; t[r][c4 + 1] = (__bf16)v.y;
    t[r][c4 + 2] = (__bf16)v.z; t[r][c4 + 3] = (__bf16)v.w;
    __syncthreads();
    bf16x4 o;
    o[0] = t[c4 + 0][r]; o[1] = t[c4 + 1][r];
    o[2] = t[c4 + 2][r]; o[3] = t[c4 + 3][r];
    *(bf16x4*)(WT + (size_t)(n0 + r) * K + k0 + c4) = o;
}

// ---------------- LayerNorm: fp32 in -> bf16 out. One block per row of 1024. ----
__global__ __launch_bounds__(256) void ln_kernel(const float* __restrict__ x,
                                                 const float* __restrict__ g,
                                                 const float* __restrict__ bta,
                                                 __bf16* __restrict__ out) {
    int row = blockIdx.x;
    int tid = threadIdx.x;
    const float4 xv = *(const float4*)(x + (size_t)row * EE + tid * 4);
    float s  = xv.x + xv.y + xv.z + xv.w;
    float ss = xv.x*xv.x + xv.y*xv.y + xv.z*xv.z + xv.w*xv.w;
    __shared__ float rs[256], rss[256];
    rs[tid] = s; rss[tid] = ss;
    __syncthreads();
    for (int st = 128; st > 0; st >>= 1) {
        if (tid < st) { rs[tid] += rs[tid+st]; rss[tid] += rss[tid+st]; }
        __syncthreads();
    }
    float mean = rs[0] * (1.0f / EE);
    float var  = rss[0] * (1.0f / EE) - mean * mean;
    float rstd = rsqrtf(var + 1e-5f);
    const float4 gv = *(const float4*)(g + tid * 4);
    const float4 bv = *(const float4*)(bta + tid * 4);
    bf16x4 ov;
    ov[0] = (__bf16)((xv.x - mean) * rstd * gv.x + bv.x);
    ov[1] = (__bf16)((xv.y - mean) * rstd * gv.y + bv.y);
    ov[2] = (__bf16)((xv.z - mean) * rstd * gv.z + bv.z);
    ov[3] = (__bf16)((xv.w - mean) * rstd * gv.w + bv.w);
    *(bf16x4*)(out + (size_t)row * EE + tid * 4) = ov;
}

// ---------------- pipelined GEMM (QKV mode adds V-transpose epilogue) ------------
// R17-exact. NBUF LDS buffers, prefetch DEPTH=NBUF-1 K-steps ahead, counted
// vmcnt, raw s_barrier. XOR slot swizzle (conflicts=0). ATOMIC: split-K x2.
template<int TM, int TN, bool GELU, bool RESID, bool QKV, bool ATOMIC, typename CT>
__global__ __launch_bounds__(256) void gemm_bt_kernel(const __bf16* __restrict__ A,
                                                      const __bf16* __restrict__ BT,
                                                      const float* __restrict__ bias,
                                                      const float* resid, CT* C,
                                                      __bf16* vT,
                                                      int M, int N, int K) {
    constexpr int MT = TM / 32;
    constexpr int NT = TN / 32;
    constexpr int LOADS = TM / 64 + TN / 64;   // global_load_lds per thread per stage
    constexpr int NBUF  = ATOMIC ? 3 : ((LOADS <= 3) ? 4 : 3);
    constexpr int DEPTH = NBUF - 1;
    constexpr int WAITN = (DEPTH - 1) * LOADS;
    __shared__ __align__(16) __bf16 As[NBUF][TM][32];
    __shared__ __align__(16) __bf16 Bs[NBUF][TN][32];
    int tid = threadIdx.x, wave = tid >> 6, lane = tid & 63;
    int quad = lane >> 4, l16 = lane & 15;
    int wm = wave >> 1, wn = wave & 1;
    int m0 = blockIdx.y * TM, n0 = blockIdx.x * TN;

    const int klen = ATOMIC ? (K >> 1) : K;
    const int koff = ATOMIC ? (int)blockIdx.z * klen : 0;

    f32x4 acc[MT][NT] = {};

    int srow = wave * 16 + (lane >> 2);
    // pre-swizzled global source column: phys slot lane&3 at row ..(lane>>2)
    // must hold logical slot (lane&3)^((row>>1)&3) = (lane&3)^((lane>>3)&3)
    int scol = (((lane & 3) ^ ((lane >> 3) & 3)) * 8);
    // ds_read column for logical slot `quad` of row ..+l16
    int xcol = ((quad ^ ((l16 >> 1) & 3)) * 8);

    auto STAGE = [&](int buf, int kt) {
        int kb = koff + (kt << 5);
#pragma unroll
        for (int p = 0; p < TM / 64; p++) {
            const __bf16* g = A + (size_t)(m0 + p * 64 + srow) * K + kb + scol;
            __builtin_amdgcn_global_load_lds((AS1 const void*)g,
                                             (AS3 void*)&As[buf][p * 64 + wave * 16][0],
                                             16, 0, 0);
        }
#pragma unroll
        for (int p = 0; p < TN / 64; p++) {
            const __bf16* g = BT + (size_t)(n0 + p * 64 + srow) * K + kb + scol;
            __builtin_amdgcn_global_load_lds((AS1 const void*)g,
                                             (AS3 void*)&Bs[buf][p * 64 + wave * 16][0],
                                             16, 0, 0);
        }
    };

    auto COMPUTE = [&](int cur) {
        bf16x8 af[MT], bfr[NT];
#pragma unroll
        for (int mt = 0; mt < MT; mt++)
            af[mt] = *(const bf16x8*)(&As[cur][wm * (MT * 16) + mt * 16 + l16][xcol]);
#pragma unroll
        for (int nt = 0; nt < NT; nt++)
            bfr[nt] = *(const bf16x8*)(&Bs[cur][wn * (NT * 16) + nt * 16 + l16][xcol]);
#pragma unroll
        for (int mt = 0; mt < MT; mt++)
#pragma unroll
            for (int nt = 0; nt < NT; nt++)
                acc[mt][nt] = __builtin_amdgcn_mfma_f32_16x16x32_bf16(af[mt], bfr[nt],
                                                                      acc[mt][nt], 0, 0, 0);
    };

    const int nk = klen >> 5;
#pragma unroll
    for (int i = 0; i < DEPTH; ++i) STAGE(i, i);
    vm_wait<WAITN>();               // stage(0) landed; rest stay in flight
    __builtin_amdgcn_s_barrier();

    int t = 0;
    for (; t + DEPTH < nk; ++t) {
        STAGE((t + DEPTH) % NBUF, t + DEPTH);
        COMPUTE(t % NBUF);
        vm_wait<WAITN>();           // stage(t+1) landed; newer stages in flight
        __builtin_amdgcn_s_barrier();
    }
    for (; t < nk; ++t) {           // tail: nothing left to issue
        COMPUTE(t % NBUF);
        if (t + 1 < nk) {
            int rem = nk - 2 - t;   // stages in flight beyond t+1
            if (rem >= 1) vm_wait<LOADS>();
            else          vm_wait<0>();
            __builtin_amdgcn_s_barrier();
        }
    }

#pragma unroll
    for (int nt = 0; nt < NT; nt++) {
        int c = n0 + wn * (NT * 16) + nt * 16 + l16;
        float bv = (!ATOMIC || blockIdx.z == 0) ? bias[c] : 0.0f;
#pragma unroll
        for (int mt = 0; mt < MT; mt++) {
#pragma unroll
            for (int r = 0; r < 4; r++) {
                int row = m0 + wm * (MT * 16) + mt * 16 + quad * 4 + r;
                float v = acc[mt][nt][r] + bv;
                if (GELU)  v = gelu_fast(v);
                if (RESID) v += resid[(size_t)row * N + c];
                if (ATOMIC) {
                    atomicAdd((float*)&C[(size_t)row * N + c], v);
                } else if (!QKV) {
                    C[(size_t)row * N + c] = (CT)v;
                } else {
                    if (c < 2 * EE) {
                        ((__bf16*)C)[(size_t)row * (2 * EE) + c] = (__bf16)v;
                    } else {
                        int cv = c - 2 * EE;          // cv = h*64 + d
                        int bb = row >> 11, tt = row & (TT - 1);
                        vT[((size_t)(bb * NH + (cv >> 6)) * HD + (cv & 63)) * TT + tt] =
                            (__bf16)v;
                    }
                }
            }
        }
    }
}

// ---------------- MFMA flash attention (R19: XCD-clustered (h,b), setprio) ------
// qkv: [b][t][2E] (Q at h*64, K at EE+h*64). vT: [b][h][d][T].
// 1-D grid of 512; lin%8 = XCD (dispatch round-robin), each XCD owns 4 whole
// (h,b) pairs (64 blocks = 4 pairs x 16 q-slots) so each head's 512KB K/V is
// L2-resident on one XCD instead of 8x-replicated. Paired q-tiles: slot qidx
// handles qt=(31-qidx) then qt=qidx -> exactly 17 iters per block. Inner loop
// byte-identical to R12/R17 except setprio around the MFMA clusters.
__global__ __launch_bounds__(256) void flash_attn_kernel(const __bf16* __restrict__ qkv,
                                                         const __bf16* __restrict__ vT,
                                                         __bf16* __restrict__ out) {
    int lin = blockIdx.x;                    // 0..511, dispatch order
    int xcd = lin & 7, slot = lin >> 3;      // 64 slots per XCD
    int pair = xcd * 4 + (slot >> 4);        // 0..31
    int qidx = slot & 15;                    // 0..15
    int h = pair & 15, b = pair >> 4;

    int tid = threadIdx.x, wave = tid >> 6, lane = tid & 63;
    int quad = lane >> 4, l16 = lane & 15;

    __shared__ __align__(16) __bf16 Ks[128 * 72];
    __shared__ __align__(16) __bf16 Ps[4][16 * 136];

    size_t base = (size_t)b * TT * (2 * EE);

    int srow = tid >> 3;            // 0..31
    int scol = (tid & 7) * 8;
    const __bf16* kbase  = qkv + base + EE + h * HD + scol;
    const __bf16* vrow = vT + (size_t)(b * NH + h) * HD * TT + (size_t)l16 * TT + quad * 8;
    __bf16* Psw = &Ps[wave][0];

    for (int pass = 0; pass < 2; pass++) {
        int qt = pass == 0 ? (31 - qidx) : qidx;
        int q0 = qt * 64;

        // Q A-fragments: A[m=l16][k=quad*8+j]
        int qrow = q0 + wave * 16 + l16;
        const __bf16* qp = qkv + base + (size_t)qrow * (2 * EE) + h * HD;
        bf16x8 aq0 = *(const bf16x8*)(qp + quad * 8);
        bf16x8 aq1 = *(const bf16x8*)(qp + 32 + quad * 8);

        f32x4 oacc[4] = {};
        float lsum[4] = {0.f, 0.f, 0.f, 0.f};
        int qg_base = q0 + wave * 16 + quad * 4;

        int nIter = (qt >> 1) + 1;

        bf16x8 kr[4];
#pragma unroll
        for (int p = 0; p < 4; p++)
            kr[p] = *(const bf16x8*)(kbase + (size_t)(32 * p + srow) * (2 * EE));

        for (int kt = 0; kt < nIter; ++kt) {
            int k0 = kt * 128;
            // ---- stage K ----
#pragma unroll
            for (int p = 0; p < 4; p++)
                *(bf16x8*)(&Ks[(32 * p + srow) * 72 + scol]) = kr[p];
            __syncthreads();  // B1

            // ---- issue this tile's V fragments (latency hides under QK+exp) ----
            bf16x8 vf[4][4];
#pragma unroll
            for (int dt = 0; dt < 4; dt++)
#pragma unroll
                for (int w = 0; w < 4; w++)
                    vf[dt][w] = *(const bf16x8*)(vrow + (size_t)dt * (16 * TT) + k0 + w * 32);

            // ---- prefetch next K tile ----
            if (kt < nIter - 1) {
                int kn = k0 + 128;
#pragma unroll
                for (int p = 0; p < 4; p++)
                    kr[p] = *(const bf16x8*)(kbase + (size_t)(kn + 32 * p + srow) * (2 * EE));
            }

            // ---- S = Q K^T over 128 keys ----
            f32x4 s[8];
            __builtin_amdgcn_s_setprio(1);
#pragma unroll
            for (int nt = 0; nt < 8; nt++) {
                bf16x8 bk0 = *(const bf16x8*)(&Ks[(nt * 16 + l16) * 72 + quad * 8]);
                bf16x8 bk1 = *(const bf16x8*)(&Ks[(nt * 16 + l16) * 72 + 32 + quad * 8]);
                f32x4 z = {};
                z = __builtin_amdgcn_mfma_f32_16x16x32_bf16(aq0, bk0, z, 0, 0, 0);
                s[nt] = __builtin_amdgcn_mfma_f32_16x16x32_bf16(aq1, bk1, z, 0, 0, 0);
            }
            __builtin_amdgcn_s_setprio(0);

            // ---- p = exp(s/8) (m=0; bounded, clamp), private swizzled Ps ----
            bool maskt = (kt == nIter - 1);
#pragma unroll
            for (int nt = 0; nt < 8; nt++) {
                int key = k0 + nt * 16 + l16;
                int cb = 2 * nt + (l16 >> 3);
#pragma unroll
                for (int r = 0; r < 4; r++) {
                    float p;
                    if (maskt && key > qg_base + r) p = 0.0f;
                    else p = __expf(fminf(s[nt][r] * 0.125f, 30.0f));
                    lsum[r] += p;
                    int q = quad * 4 + r;
                    int col = (((cb & 8) | ((cb - 2 * q) & 7)) << 3) | (l16 & 7);
                    Psw[q * 136 + col] = (__bf16)p;
                }
            }

            // ---- O += P V : Ps private (no barrier), V already in registers ----
            __builtin_amdgcn_s_setprio(1);
#pragma unroll
            for (int w = 0; w < 4; w++) {
                int cbr = 4 * w + quad;
                int colr = ((cbr & 8) | ((cbr - 2 * l16) & 7)) << 3;
                bf16x8 ap = *(const bf16x8*)(&Psw[l16 * 136 + colr]);
#pragma unroll
                for (int dt = 0; dt < 4; dt++)
                    oacc[dt] = __builtin_amdgcn_mfma_f32_16x16x32_bf16(ap, vf[dt][w],
                                                                       oacc[dt], 0, 0, 0);
            }
            __builtin_amdgcn_s_setprio(0);
            __syncthreads();  // B2: Ks reads done before next stage
        }

        // ---- deferred l reduce + epilogue for this q-tile ----
#pragma unroll
        for (int off = 1; off < 16; off <<= 1)
#pragma unroll
            for (int r = 0; r < 4; r++) lsum[r] += __shfl_xor(lsum[r], off);
#pragma unroll
        for (int dt = 0; dt < 4; dt++) {
#pragma unroll
            for (int r = 0; r < 4; r++) {
                int qg = qg_base + r;
                out[((size_t)b * TT + qg) * EE + h * HD + dt * 16 + l16] =
                    (__bf16)(oacc[dt][r] / lsum[r]);
            }
        }
    }
}

extern "C" void kernel_launch(void* const* d_in, const int* in_sizes, int n_in,
                              void* d_out, int out_size, void* d_ws, size_t ws_size,
                              hipStream_t stream) {
    const float* x     = (const float*)d_in[0];
    const float* ln1g  = (const float*)d_in[1];
    const float* ln1b  = (const float*)d_in[2];
    const float* ln2g  = (const float*)d_in[3];
    const float* ln2b  = (const float*)d_in[4];
    const float* Wqkv  = (const float*)d_in[5];
    const float* bqkv  = (const float*)d_in[6];
    const float* Wo    = (const float*)d_in[7];
    const float* bo    = (const float*)d_in[8];
    const float* Wfc   = (const float*)d_in[9];
    const float* bfc   = (const float*)d_in[10];
    const float* Wproj = (const float*)d_in[11];
    const float* bproj = (const float*)d_in[12];
    float* out = (float*)d_out;

    const int M = 2 * TT;  // 4096 tokens

    // Workspace (bf16, 50.4 MB), lifetime-aliased:
    //   regQ [0,16.8M): qkv(QK, 8.4M) | vT(4.2M) | WqkvT(3.15M) | WoT(1.05M)
    //                   -> all dead before ff [16.8M] overwrites
    //   regS [16.8M,21M): h1 -> atn -> h2 -> WprojT
    //   WfcT [21M,25.2M);  x1 (fp32) lives in d_out
    __bf16* ws = (__bf16*)d_ws;
    __bf16* regQ   = ws;
    __bf16* regS   = ws + 16777216;
    __bf16* WfcT   = ws + 20971520;
    __bf16* qkv    = regQ;                  //  8,388,608
    __bf16* vT     = regQ + 8388608;        //  4,194,304
    __bf16* WqkvT  = regQ + 12582912;       //  3,145,728
    __bf16* WoT    = regQ + 15728640;       //  1,048,576
    __bf16* ff     = regQ;
    __bf16* h1 = regS, *atn = regS, *h2 = regS;
    __bf16* WprojT = regS;
    float*  x1 = out;

    // merged: Wqkv + Wo + Wfc transposes in one launch (8192 tiles)
    convt3_kernel<<<8192, 256, 0, stream>>>(Wqkv, WqkvT, Wo, WoT, Wfc, WfcT);

    ln_kernel<<<M, 256, 0, stream>>>(x, ln1g, ln1b, h1);
    gemm_bt_kernel<128, 128, false, false, true, false, __bf16>
        <<<dim3(3 * EE / 128, M / 128), 256, 0, stream>>>(
        h1, WqkvT, bqkv, nullptr, qkv, vT, M, 3 * EE, EE);
    flash_attn_kernel<<<512, 256, 0, stream>>>(qkv, vT, atn);
    gemm_bt_kernel<128, 64, false, true, false, false, float>
        <<<dim3(EE / 64, M / 128), 256, 0, stream>>>(
        atn, WoT, bo, x, x1, nullptr, M, EE, EE);
    ln_kernel<<<M, 256, 0, stream>>>(x1, ln2g, ln2b, h2);
    gemm_bt_kernel<128, 128, true, false, false, false, __bf16>
        <<<dim3(4 * EE / 128, M / 128), 256, 0, stream>>>(
        h2, WfcT, bfc, nullptr, ff, nullptr, M, 4 * EE, EE);
    convt_kernel<<<dim3(EE / 32, 4 * EE / 32), 256, 0, stream>>>(Wproj, WprojT, 4 * EE, EE);
    // split-K x2: out already holds x1 (residual); halves atomicAdd partials.
    gemm_bt_kernel<128, 64, false, false, false, true, float>
        <<<dim3(EE / 64, M / 128, 2), 256, 0, stream>>>(
        ff, WprojT, bproj, nullptr, out, nullptr, M, EE, 4 * EE);
}